// Round 6
// baseline (307.782 us; speedup 1.0000x reference)
//
#include <hip/hip_runtime.h>
#include <math.h>

// Problem constants (B,H,W,C = 16,32,32,512; 32 groups)
#define BATCH 16
#define NTOK  1024
#define CH    512
#define NGRP  32
#define GSZ   16
#define EPSV  1e-3f
#define MTOT  (BATCH*NTOK)          // 16384
#define SCALE 0.04419417382415922f  // 512^-0.5
#define SEXP  (SCALE*1.4426950408889634f)   // scale*log2(e), for exp2

typedef unsigned short u16;
typedef __attribute__((ext_vector_type(4))) float f32x4;
typedef __attribute__((ext_vector_type(8))) short s16x8;

__device__ __forceinline__ u16 f2bf(float f) {           // RNE float->bf16
    union { float f; unsigned u; } x{f};
    unsigned r = x.u + 0x7fff + ((x.u >> 16) & 1);
    return (u16)(r >> 16);
}

__device__ __forceinline__ void gld16(const u16* g, u16* l) {
    __builtin_amdgcn_global_load_lds(
        (const __attribute__((address_space(1))) void*)g,
        (__attribute__((address_space(3))) void*)l, 16, 0, 0);
}

#define MFMA16 __builtin_amdgcn_mfma_f32_16x16x32_bf16

// ---------------------------------------------------------------- group-norm stats
__global__ __launch_bounds__(256) void gn_stats(const float* __restrict__ x,
                                                float2* __restrict__ stats) {
    int bg = blockIdx.x;             // batch*32 + group
    int b = bg >> 5, g = bg & 31;
    const float* base = x + (size_t)b * NTOK * CH + g * GSZ;
    float s = 0.f, ss = 0.f;
    for (int i = threadIdx.x; i < 4096; i += 256) {
        int p = i >> 2, c4 = i & 3;
        float4 v = *(const float4*)(base + (size_t)p * CH + c4 * 4);
        s  += v.x + v.y + v.z + v.w;
        ss += v.x * v.x + v.y * v.y + v.z * v.z + v.w * v.w;
    }
    for (int off = 32; off; off >>= 1) {
        s  += __shfl_down(s, off);
        ss += __shfl_down(ss, off);
    }
    __shared__ float2 part[4];
    if ((threadIdx.x & 63) == 0) part[threadIdx.x >> 6] = make_float2(s, ss);
    __syncthreads();
    if (threadIdx.x == 0) {
        float S = 0.f, SS = 0.f;
        for (int i = 0; i < 4; i++) { S += part[i].x; SS += part[i].y; }
        float mean = S * (1.f / 16384.f);
        float var  = SS * (1.f / 16384.f) - mean * mean;
        stats[bg] = make_float2(mean, rsqrtf(var + EPSV));
    }
}

// ---------------------------------------------------------------- apply norm -> xn(f32) + xnb(bf16)
__global__ __launch_bounds__(256) void gn_apply(const float* __restrict__ x,
                                                const float2* __restrict__ stats,
                                                const float* __restrict__ gamma,
                                                const float* __restrict__ beta,
                                                float* __restrict__ xn,
                                                u16* __restrict__ xnb) {
    size_t total = (size_t)MTOT * CH / 4;
    for (size_t i4 = (size_t)blockIdx.x * 256 + threadIdx.x; i4 < total;
         i4 += (size_t)gridDim.x * 256) {
        size_t flat = i4 * 4;
        int c = (int)(flat & (CH - 1));
        int b = (int)(flat >> 19);
        int g = c >> 4;
        float2 st = stats[(b << 5) + g];
        float4 xv = *(const float4*)(x + flat);
        float4 gv = *(const float4*)(gamma + c);
        float4 bv = *(const float4*)(beta + c);
        float4 o;
        o.x = (xv.x - st.x) * st.y * gv.x + bv.x;
        o.y = (xv.y - st.x) * st.y * gv.y + bv.y;
        o.z = (xv.z - st.x) * st.y * gv.z + bv.z;
        o.w = (xv.w - st.x) * st.y * gv.w + bv.w;
        *(float4*)(xn + flat) = o;
        uint2 h;
        h.x = (unsigned)f2bf(o.x) | ((unsigned)f2bf(o.y) << 16);
        h.y = (unsigned)f2bf(o.z) | ((unsigned)f2bf(o.w) << 16);
        *(uint2*)(xnb + flat) = h;
    }
}

// ---------------------------------------------------------------- weights: transpose f32->bf16, all 4 in one dispatch
__global__ __launch_bounds__(256) void weights_prep(
    const float* __restrict__ Wq, const float* __restrict__ Wk,
    const float* __restrict__ Wv, const float* __restrict__ Wp,
    u16* __restrict__ WTqkv, u16* __restrict__ WTp) {
    int z = blockIdx.z;
    const float* src = z == 0 ? Wq : z == 1 ? Wk : z == 2 ? Wv : Wp;
    u16* dst = z < 3 ? WTqkv + (size_t)z * CH * CH : WTp;
    __shared__ u16 tile[64][66];
    int r0 = blockIdx.y * 64, c0 = blockIdx.x * 64;
    int t = threadIdx.x;
    for (int i = 0; i < 16; i++) {
        int idx = i * 256 + t;
        int r = idx >> 6, c = idx & 63;
        tile[r][c] = f2bf(src[(size_t)(r0 + r) * CH + c0 + c]);
    }
    __syncthreads();
    for (int i = 0; i < 16; i++) {
        int idx = i * 256 + t;
        int oc = idx >> 6, orr = idx & 63;
        dst[(size_t)(c0 + oc) * CH + r0 + orr] = tile[orr][oc];
    }
}

// bias concat [bq|bk|bv] -> bqkv[1536]
__global__ void prep_bias(const float* __restrict__ bq, const float* __restrict__ bk,
                          const float* __restrict__ bv, float* __restrict__ bqkv) {
    int t = blockIdx.x * 256 + threadIdx.x;   // 0..1535
    bqkv[t] = t < 512 ? bq[t] : (t < 1024 ? bk[t - 512] : bv[t - 1024]);
}

// ---------------------------------------------------------------- V slice -> V^T per batch (bf16)
__global__ __launch_bounds__(256) void vt_transpose(const u16* __restrict__ in,
                                                    u16* __restrict__ out,
                                                    int R, int C, int ldIn,
                                                    long sIn, long sOut) {
    __shared__ u16 tile[64][66];
    int z = blockIdx.z;
    in  += (size_t)z * sIn;
    out += (size_t)z * sOut;
    int r0 = blockIdx.y * 64, c0 = blockIdx.x * 64;
    int t = threadIdx.x;
    for (int i = 0; i < 16; i++) {
        int idx = i * 256 + t;
        int r = idx >> 6, c = idx & 63;
        tile[r][c] = in[(size_t)(r0 + r) * ldIn + c0 + c];
    }
    __syncthreads();
    for (int i = 0; i < 16; i++) {
        int idx = i * 256 + t;
        int oc = idx >> 6, orr = idx & 63;
        out[(size_t)(c0 + oc) * R + r0 + orr] = tile[orr][oc];
    }
}

// ---------------------------------------------------------------- bf16 MFMA GEMM  (C = alpha*A*B^T (+bias) (+res))
// 128x128 tile, 4 waves, dbuf LDS, 2-phase. Chunked XCD swizzle (nb % 8 == 0).
template <bool BIAS, bool RES, bool OUTF32>
__global__ __launch_bounds__(256) void gemm_bt(
    const u16* __restrict__ A, const u16* __restrict__ B, void* __restrict__ Cout,
    const float* __restrict__ bias, const float* __restrict__ res,
    int K, int lda, int ldb, int ldc,
    long sA, long sB, long sC, float alpha) {
    __shared__ __align__(16) u16 Asm[8192];   // 2 x 8 KB
    __shared__ __align__(16) u16 Bsm[8192];

    unsigned flat = blockIdx.x + gridDim.x * (blockIdx.y + gridDim.y * blockIdx.z);
    unsigned nb = gridDim.x * gridDim.y * gridDim.z;
    unsigned lf = (flat & 7) * (nb >> 3) + (flat >> 3);
    unsigned pb = gridDim.x * gridDim.y;
    unsigned bz = lf / pb, rem = lf - bz * pb;
    unsigned by = rem / gridDim.x, bx = rem - by * gridDim.x;

    A += (size_t)bz * sA;
    B += (size_t)bz * sB;
    size_t zc = (size_t)bz * sC;

    int t = threadIdx.x;
    int wave = t >> 6, lane = t & 63;
    int wm = wave >> 1, wn = wave & 1;
    int rowA0 = by * 128;
    int colB0 = bx * 128;

    int c16log = (lane & 3) ^ ((lane >> 3) & 3);     // pre-swizzled global source
    const u16* aG[2]; const u16* bG[2]; u16* aL[2]; u16* bL[2];
#pragma unroll
    for (int j = 0; j < 2; j++) {
        int s = wave * 2 + j;
        int row = s * 16 + (lane >> 2);
        aL[j] = Asm + s * 512;
        bL[j] = Bsm + s * 512;
        aG[j] = A + (size_t)(rowA0 + row) * lda + c16log * 8;
        bG[j] = B + (size_t)(colB0 + row) * ldb + c16log * 8;
    }

    int kg = lane >> 4;
    int aoff[4], boff[4];
#pragma unroll
    for (int i = 0; i < 4; i++) {
        int ra = wm * 64 + i * 16 + (lane & 15);
        aoff[i] = ra * 32 + (kg ^ ((ra >> 1) & 3)) * 8;
        int rb = wn * 64 + i * 16 + (lane & 15);
        boff[i] = rb * 32 + (kg ^ ((rb >> 1) & 3)) * 8;
    }

#define STG_G(buf, ktE)                          \
    {                                            \
        gld16(aG[0] + (ktE), aL[0] + (buf) * 4096); \
        gld16(aG[1] + (ktE), aL[1] + (buf) * 4096); \
        gld16(bG[0] + (ktE), bL[0] + (buf) * 4096); \
        gld16(bG[1] + (ktE), bL[1] + (buf) * 4096); \
    }

    f32x4 acc[4][4] = {};
    int nk = K >> 5;
    STG_G(0, 0);
    __syncthreads();
    for (int kt = 0; kt < nk; kt++) {
        if (kt + 1 < nk) STG_G((kt + 1) & 1, (kt + 1) * 32);
        const u16* as = Asm + (kt & 1) * 4096;
        const u16* bs = Bsm + (kt & 1) * 4096;
        s16x8 af[4], bfr[4];
#pragma unroll
        for (int i = 0; i < 4; i++) {
            af[i]  = *(const s16x8*)(as + aoff[i]);
            bfr[i] = *(const s16x8*)(bs + boff[i]);
        }
#pragma unroll
        for (int mi = 0; mi < 4; mi++)
#pragma unroll
            for (int nj = 0; nj < 4; nj++)
                acc[mi][nj] = MFMA16(af[mi], bfr[nj], acc[mi][nj], 0, 0, 0);
        __syncthreads();
    }
#undef STG_G

    int r0 = rowA0 + wm * 64 + (lane >> 4) * 4;
    int c0c = colB0 + wn * 64 + (lane & 15);
#pragma unroll
    for (int mi = 0; mi < 4; mi++) {
#pragma unroll
        for (int nj = 0; nj < 4; nj++) {
            int c = c0c + nj * 16;
            float bv = BIAS ? bias[c] : 0.f;
            f32x4 v = acc[mi][nj];
#pragma unroll
            for (int j = 0; j < 4; j++) {
                int rr = r0 + mi * 16 + j;
                float val = v[j] * alpha + bv;
                if (RES) val += res[(size_t)rr * ldc + c];
                if (OUTF32) ((float*)Cout)[zc + (size_t)rr * ldc + c] = val;
                else        ((u16*)Cout)[zc + (size_t)rr * ldc + c] = f2bf(val);
            }
        }
    }
}

// ---------------------------------------------------------------- fused flash attention
// One block per (batch, 64-row q-tile); 512 thr = 8 waves as 2 row-teams x 4 col-teams.
// Phase 1: QK^T (K dbuf 2x64KB LDS, Q-frags from L2, B-amp=2).
// Phase 2: full-row softmax (LDS cross-wave reduce).
// Phase 3/4 (x2 halves): pack P-half (64x512 bf16, granule-XOR swizzle) into LDS,
//           PV over that half with V^T chunks dbuf 2x32KB. Epilogue: coalesced ao store.
__global__ __launch_bounds__(512) void attn_fused(const u16* __restrict__ qkv,
                                                  const u16* __restrict__ vtg,
                                                  u16* __restrict__ ao) {
    __shared__ __align__(16) u16 S[65536];       // 128 KB

    unsigned flat = blockIdx.x;                  // 256 blocks
    unsigned lf = (flat & 7) * 32 + (flat >> 3); // 2 batches per XCD
    int b = lf >> 4, mt = lf & 15;

    int t = threadIdx.x, w = t >> 6, lane = t & 63;
    int rt = w >> 2, ct = w & 3;                 // row-team 0..1, col-team 0..3
    int l15 = lane & 15, kg = lane >> 4;

    const u16* kbase = qkv + (size_t)b * NTOK * 1536 + CH;
    int c16log = (lane & 3) ^ ((lane >> 3) & 3);

    // K staging: 64 segs of 16 rows; wave w stages segs w*8..w*8+7
    const u16* bG[8];
#pragma unroll
    for (int j = 0; j < 8; j++) {
        int row = (w * 8 + j) * 16 + (lane >> 2);
        bG[j] = kbase + (size_t)row * 1536 + c16log * 8;
    }
    // Q-frag row pointers (2 row-groups, frags read from global/L2 per kt)
    const u16* qp[2];
#pragma unroll
    for (int rg = 0; rg < 2; rg++)
        qp[rg] = qkv + (size_t)(b * NTOK + mt * 64 + rt * 32 + rg * 16 + l15) * 1536 + kg * 8;

    int rbb = ct * 256 + l15;                            // K B-frag base row
    int boffb = rbb * 32 + ((kg ^ ((rbb >> 1) & 3)) << 3);

    f32x4 acc1[2][16];
#pragma unroll
    for (int rg = 0; rg < 2; rg++)
#pragma unroll
        for (int nj = 0; nj < 16; nj++) acc1[rg][nj] = f32x4{0.f, 0.f, 0.f, 0.f};

#define KSTG(buf, kt)                                                        \
    { _Pragma("unroll")                                                      \
      for (int j = 0; j < 8; j++)                                            \
          gld16(bG[j] + (kt) * 32, S + (buf) * 32768 + (w * 8 + j) * 512); }

    KSTG(0, 0);
    s16x8 aqc[2], aqn[2];
    aqc[0] = *(const s16x8*)(qp[0]);
    aqc[1] = *(const s16x8*)(qp[1]);
    __syncthreads();
#pragma unroll
    for (int kt = 0; kt < 16; kt++) {
        if (kt < 15) {
            KSTG((kt + 1) & 1, kt + 1);
            aqn[0] = *(const s16x8*)(qp[0] + (kt + 1) * 32);
            aqn[1] = *(const s16x8*)(qp[1] + (kt + 1) * 32);
        }
        const u16* bb = S + (kt & 1) * 32768;
#pragma unroll
        for (int nj = 0; nj < 16; nj++) {
            s16x8 bf = *(const s16x8*)(bb + boffb + nj * 512);
            acc1[0][nj] = MFMA16(aqc[0], bf, acc1[0][nj], 0, 0, 0);
            acc1[1][nj] = MFMA16(aqc[1], bf, acc1[1][nj], 0, 0, 0);
        }
        if (kt < 15) { aqc[0] = aqn[0]; aqc[1] = aqn[1]; }
        __syncthreads();
    }
#undef KSTG

    // ---- softmax over full 1024 cols (scale folded into exp2) ----
    float* redm = (float*)S;          // [64][4]
    float* reds = redm + 256;         // [64][4]
    float mr[2][4], iv[2][4];
#pragma unroll
    for (int rg = 0; rg < 2; rg++)
#pragma unroll
        for (int j = 0; j < 4; j++) {
            float m = acc1[rg][0][j];
#pragma unroll
            for (int nj = 1; nj < 16; nj++) m = fmaxf(m, acc1[rg][nj][j]);
            for (int off = 1; off < 16; off <<= 1) m = fmaxf(m, __shfl_xor(m, off));
            mr[rg][j] = m;
        }
    if (l15 == 0) {
#pragma unroll
        for (int rg = 0; rg < 2; rg++)
#pragma unroll
            for (int j = 0; j < 4; j++)
                redm[(rt * 32 + rg * 16 + kg * 4 + j) * 4 + ct] = mr[rg][j];
    }
    __syncthreads();
#pragma unroll
    for (int rg = 0; rg < 2; rg++)
#pragma unroll
        for (int j = 0; j < 4; j++) {
            int row = rt * 32 + rg * 16 + kg * 4 + j;
            mr[rg][j] = fmaxf(fmaxf(redm[row * 4], redm[row * 4 + 1]),
                              fmaxf(redm[row * 4 + 2], redm[row * 4 + 3]));
        }
#pragma unroll
    for (int rg = 0; rg < 2; rg++)
#pragma unroll
        for (int j = 0; j < 4; j++) {
            float s = 0.f;
#pragma unroll
            for (int nj = 0; nj < 16; nj++) {
                float e = exp2f((acc1[rg][nj][j] - mr[rg][j]) * SEXP);
                acc1[rg][nj][j] = e;
                s += e;
            }
            for (int off = 1; off < 16; off <<= 1) s += __shfl_xor(s, off);
            if (l15 == 0) reds[(rt * 32 + rg * 16 + kg * 4 + j) * 4 + ct] = s;
        }
    __syncthreads();
#pragma unroll
    for (int rg = 0; rg < 2; rg++)
#pragma unroll
        for (int j = 0; j < 4; j++) {
            int row = rt * 32 + rg * 16 + kg * 4 + j;
            iv[rg][j] = 1.f / (reds[row * 4] + reds[row * 4 + 1] +
                               reds[row * 4 + 2] + reds[row * 4 + 3]);
        }
    __syncthreads();   // all reads of redm/reds done before pack overwrites S

    // ---- PV: two 512-k halves; P-half packed in S[0,64KB), V^T dbuf in S[64,128KB) ----
    const u16* vG[4];
#pragma unroll
    for (int sj = 0; sj < 4; sj++) {
        int chrow = (w * 4 + sj) * 16 + (lane >> 2);
        vG[sj] = vtg + ((size_t)b * 512 + chrow) * 1024 + c16log * 8;
    }
#define VSTG(buf, hf, c)                                                     \
    { _Pragma("unroll")                                                      \
      for (int sj = 0; sj < 4; sj++)                                         \
          gld16(vG[sj] + (hf) * 512 + (c) * 32,                              \
                S + 32768 + (buf) * 16384 + (w * 4 + sj) * 512); }

    f32x4 acc2[2][8];
#pragma unroll
    for (int rg = 0; rg < 2; rg++)
#pragma unroll
        for (int cj = 0; cj < 8; cj++) acc2[rg][cj] = f32x4{0.f, 0.f, 0.f, 0.f};

    int prow[2] = {rt * 32 + l15, rt * 32 + 16 + l15};   // A-frag rows
    int chl = ct * 128 + l15;                            // B-frag base ch
    int voffb = chl * 32 + ((kg ^ ((chl >> 1) & 3)) << 3);

    for (int hf = 0; hf < 2; hf++) {
        VSTG(0, hf, 0);                     // stage first V chunk under the pack
        if ((ct >> 1) == hf) {              // this wave's cols belong to half hf
            int kb16 = (ct & 1) * 256;
#pragma unroll
            for (int rg = 0; rg < 2; rg++)
#pragma unroll
                for (int nj = 0; nj < 16; nj++) {
                    int klocal = kb16 + nj * 16 + l15;
                    int g = klocal >> 3, ko = klocal & 7;
#pragma unroll
                    for (int j = 0; j < 4; j++) {
                        int row = rt * 32 + rg * 16 + kg * 4 + j;
                        S[row * 512 + (((g ^ (row & 7))) << 3) + ko] =
                            f2bf(acc1[rg][nj][j] * iv[rg][j]);
                    }
                }
        }
        __syncthreads();
        for (int c = 0; c < 16; c++) {
            if (c < 15) VSTG((c + 1) & 1, hf, c + 1);
            const u16* vb = S + 32768 + (c & 1) * 16384;
            s16x8 pa[2];
#pragma unroll
            for (int rg = 0; rg < 2; rg++) {
                int row = prow[rg];
                pa[rg] = *(const s16x8*)(S + row * 512 + (((c * 4 + kg) ^ (row & 7)) << 3));
            }
#pragma unroll
            for (int cj = 0; cj < 8; cj++) {
                s16x8 vf = *(const s16x8*)(vb + voffb + cj * 512);
                acc2[0][cj] = MFMA16(pa[0], vf, acc2[0][cj], 0, 0, 0);
                acc2[1][cj] = MFMA16(pa[1], vf, acc2[1][cj], 0, 0, 0);
            }
            __syncthreads();
        }
    }
#undef VSTG

    // ---- epilogue: repack acc2 through S (granule-swizzled) -> coalesced uint4 stores ----
#pragma unroll
    for (int rg = 0; rg < 2; rg++)
#pragma unroll
        for (int cj = 0; cj < 8; cj++)
#pragma unroll
            for (int j = 0; j < 4; j++) {
                int row = rt * 32 + rg * 16 + kg * 4 + j;
                int ch = ct * 128 + cj * 16 + l15;
                S[row * 512 + ((((ch >> 3) ^ (row & 7))) << 3) + (ch & 7)] =
                    f2bf(acc2[rg][cj][j]);
            }
    __syncthreads();
    u16* aop = ao + (size_t)(b * NTOK + mt * 64) * 512;
#pragma unroll
    for (int i = 0; i < 8; i++) {
        int f = i * 512 + t;              // granule index 0..4095
        int row = f >> 6, g = f & 63;
        uint4 v = *(const uint4*)(S + row * 512 + g * 8);
        *(uint4*)(aop + (size_t)row * 512 + ((g ^ (row & 7)) << 3)) = v;
    }
}

// ---------------------------------------------------------------- launch
extern "C" void kernel_launch(void* const* d_in, const int* in_sizes, int n_in,
                              void* d_out, int out_size, void* d_ws, size_t ws_size,
                              hipStream_t stream) {
    const float* x     = (const float*)d_in[0];
    const float* gamma = (const float*)d_in[1];
    const float* beta  = (const float*)d_in[2];
    const float* Wq    = (const float*)d_in[3];
    const float* bq    = (const float*)d_in[4];
    const float* Wk    = (const float*)d_in[5];
    const float* bk    = (const float*)d_in[6];
    const float* Wv    = (const float*)d_in[7];
    const float* bv    = (const float*)d_in[8];
    const float* Wp    = (const float*)d_in[9];
    const float* bp    = (const float*)d_in[10];
    float* out = (float*)d_out;

    const size_t SZ  = (size_t)MTOT * CH;          // 8,388,608
    const size_t NSZ = (size_t)NTOK * CH;          // per-batch activation

    char* p = (char*)d_ws;
    float*  xn    = (float*)p;   p += SZ * 4;                     // 33.5 MB
    u16*    xnb   = (u16*)p;     p += SZ * 2;                     // 16.8 MB
    u16*    qkvb  = (u16*)p;     p += (size_t)MTOT * 3 * CH * 2;  // 50.3 MB
    u16*    vt    = (u16*)p;     p += SZ * 2;                     // 16.8 MB
    u16*    ao    = (u16*)p;     p += SZ * 2;                     // 16.8 MB
    u16*    WTqkv = (u16*)p;     p += (size_t)3 * CH * CH * 2;    // 1.5 MB
    u16*    WTp   = (u16*)p;     p += (size_t)CH * CH * 2;        // 0.5 MB
    float*  bqkv  = (float*)p;   p += 3 * CH * 4;
    float2* stats = (float2*)p;

    dim3 blk(256);

    gn_stats<<<BATCH * NGRP, blk, 0, stream>>>(x, stats);
    gn_apply<<<2048, blk, 0, stream>>>(x, stats, gamma, beta, xn, xnb);
    weights_prep<<<dim3(8, 8, 4), blk, 0, stream>>>(Wq, Wk, Wv, Wp, WTqkv, WTp);
    prep_bias<<<6, blk, 0, stream>>>(bq, bk, bv, bqkv);

    // fused QKV: [16384x512] @ [512x1536] + bias -> qkvb bf16 (row stride 1536)
    gemm_bt<true, false, false><<<dim3(12, 128, 1), blk, 0, stream>>>(
        xnb, WTqkv, qkvb, bqkv, nullptr, CH, CH, CH, 3 * CH, 0, 0, 0, 1.f);

    // V slice -> V^T per batch
    vt_transpose<<<dim3(8, 16, BATCH), blk, 0, stream>>>(
        qkvb + 2 * CH, vt, NTOK, CH, 3 * CH, (long)NTOK * 3 * CH, (long)NSZ);

    // fused flash attention: scores+softmax+PV -> ao bf16
    attn_fused<<<256, 512, 0, stream>>>(qkvb, vt, ao);

    // proj + bias + residual(xn f32) -> out f32
    gemm_bt<true, true, true><<<dim3(4, 128, 1), blk, 0, stream>>>(
        ao, WTp, out, bp, xn, CH, CH, CH, CH, 0, 0, 0, 1.f);
}

// Round 7
// 283.190 us; speedup vs baseline: 1.0868x; 1.0868x over previous
//
#include <hip/hip_runtime.h>
#include <math.h>

// Problem constants (B,H,W,C = 16,32,32,512; 32 groups)
#define BATCH 16
#define NTOK  1024
#define CH    512
#define NGRP  32
#define GSZ   16
#define EPSV  1e-3f
#define MTOT  (BATCH*NTOK)          // 16384
#define SCALE 0.04419417382415922f  // 512^-0.5
#define SEXP  (SCALE*1.4426950408889634f)   // scale*log2(e), for exp2

typedef unsigned short u16;
typedef __attribute__((ext_vector_type(4))) float f32x4;
typedef __attribute__((ext_vector_type(8))) short s16x8;

__device__ __forceinline__ u16 f2bf(float f) {           // RNE float->bf16
    union { float f; unsigned u; } x{f};
    unsigned r = x.u + 0x7fff + ((x.u >> 16) & 1);
    return (u16)(r >> 16);
}

__device__ __forceinline__ void gld16(const u16* g, u16* l) {
    __builtin_amdgcn_global_load_lds(
        (const __attribute__((address_space(1))) void*)g,
        (__attribute__((address_space(3))) void*)l, 16, 0, 0);
}

#define MFMA16 __builtin_amdgcn_mfma_f32_16x16x32_bf16

// ---------------------------------------------------------------- group-norm stats
__global__ __launch_bounds__(256) void gn_stats(const float* __restrict__ x,
                                                float2* __restrict__ stats) {
    int bg = blockIdx.x;             // batch*32 + group
    int b = bg >> 5, g = bg & 31;
    const float* base = x + (size_t)b * NTOK * CH + g * GSZ;
    float s = 0.f, ss = 0.f;
    for (int i = threadIdx.x; i < 4096; i += 256) {
        int p = i >> 2, c4 = i & 3;
        float4 v = *(const float4*)(base + (size_t)p * CH + c4 * 4);
        s  += v.x + v.y + v.z + v.w;
        ss += v.x * v.x + v.y * v.y + v.z * v.z + v.w * v.w;
    }
    for (int off = 32; off; off >>= 1) {
        s  += __shfl_down(s, off);
        ss += __shfl_down(ss, off);
    }
    __shared__ float2 part[4];
    if ((threadIdx.x & 63) == 0) part[threadIdx.x >> 6] = make_float2(s, ss);
    __syncthreads();
    if (threadIdx.x == 0) {
        float S = 0.f, SS = 0.f;
        for (int i = 0; i < 4; i++) { S += part[i].x; SS += part[i].y; }
        float mean = S * (1.f / 16384.f);
        float var  = SS * (1.f / 16384.f) - mean * mean;
        stats[bg] = make_float2(mean, rsqrtf(var + EPSV));
    }
}

// ---------------------------------------------------------------- apply norm -> xn(f32) + xnb(bf16)
__global__ __launch_bounds__(256) void gn_apply(const float* __restrict__ x,
                                                const float2* __restrict__ stats,
                                                const float* __restrict__ gamma,
                                                const float* __restrict__ beta,
                                                float* __restrict__ xn,
                                                u16* __restrict__ xnb) {
    size_t total = (size_t)MTOT * CH / 4;
    for (size_t i4 = (size_t)blockIdx.x * 256 + threadIdx.x; i4 < total;
         i4 += (size_t)gridDim.x * 256) {
        size_t flat = i4 * 4;
        int c = (int)(flat & (CH - 1));
        int b = (int)(flat >> 19);
        int g = c >> 4;
        float2 st = stats[(b << 5) + g];
        float4 xv = *(const float4*)(x + flat);
        float4 gv = *(const float4*)(gamma + c);
        float4 bv = *(const float4*)(beta + c);
        float4 o;
        o.x = (xv.x - st.x) * st.y * gv.x + bv.x;
        o.y = (xv.y - st.x) * st.y * gv.y + bv.y;
        o.z = (xv.z - st.x) * st.y * gv.z + bv.z;
        o.w = (xv.w - st.x) * st.y * gv.w + bv.w;
        *(float4*)(xn + flat) = o;
        uint2 h;
        h.x = (unsigned)f2bf(o.x) | ((unsigned)f2bf(o.y) << 16);
        h.y = (unsigned)f2bf(o.z) | ((unsigned)f2bf(o.w) << 16);
        *(uint2*)(xnb + flat) = h;
    }
}

// ---------------------------------------------------------------- weights: transpose f32->bf16, all 4 in one dispatch
__global__ __launch_bounds__(256) void weights_prep(
    const float* __restrict__ Wq, const float* __restrict__ Wk,
    const float* __restrict__ Wv, const float* __restrict__ Wp,
    u16* __restrict__ WTqkv, u16* __restrict__ WTp) {
    int z = blockIdx.z;
    const float* src = z == 0 ? Wq : z == 1 ? Wk : z == 2 ? Wv : Wp;
    u16* dst = z < 3 ? WTqkv + (size_t)z * CH * CH : WTp;
    __shared__ u16 tile[64][66];
    int r0 = blockIdx.y * 64, c0 = blockIdx.x * 64;
    int t = threadIdx.x;
    for (int i = 0; i < 16; i++) {
        int idx = i * 256 + t;
        int r = idx >> 6, c = idx & 63;
        tile[r][c] = f2bf(src[(size_t)(r0 + r) * CH + c0 + c]);
    }
    __syncthreads();
    for (int i = 0; i < 16; i++) {
        int idx = i * 256 + t;
        int oc = idx >> 6, orr = idx & 63;
        dst[(size_t)(c0 + oc) * CH + r0 + orr] = tile[orr][oc];
    }
}

// bias concat [bq|bk|bv] -> bqkv[1536]
__global__ void prep_bias(const float* __restrict__ bq, const float* __restrict__ bk,
                          const float* __restrict__ bv, float* __restrict__ bqkv) {
    int t = blockIdx.x * 256 + threadIdx.x;   // 0..1535
    bqkv[t] = t < 512 ? bq[t] : (t < 1024 ? bk[t - 512] : bv[t - 1024]);
}

// ---------------------------------------------------------------- V slice -> V^T per batch (bf16)
__global__ __launch_bounds__(256) void vt_transpose(const u16* __restrict__ in,
                                                    u16* __restrict__ out,
                                                    int R, int C, int ldIn,
                                                    long sIn, long sOut) {
    __shared__ u16 tile[64][66];
    int z = blockIdx.z;
    in  += (size_t)z * sIn;
    out += (size_t)z * sOut;
    int r0 = blockIdx.y * 64, c0 = blockIdx.x * 64;
    int t = threadIdx.x;
    for (int i = 0; i < 16; i++) {
        int idx = i * 256 + t;
        int r = idx >> 6, c = idx & 63;
        tile[r][c] = in[(size_t)(r0 + r) * ldIn + c0 + c];
    }
    __syncthreads();
    for (int i = 0; i < 16; i++) {
        int idx = i * 256 + t;
        int oc = idx >> 6, orr = idx & 63;
        out[(size_t)(c0 + oc) * R + r0 + orr] = tile[orr][oc];
    }
}

// ---------------------------------------------------------------- bf16 MFMA GEMM  (C = alpha*A*B^T (+bias) (+res))
// 128x128 tile, 4 waves, dbuf LDS, 2-phase. Chunked XCD swizzle (nb % 8 == 0).
template <bool BIAS, bool RES, bool OUTF32>
__global__ __launch_bounds__(256) void gemm_bt(
    const u16* __restrict__ A, const u16* __restrict__ B, void* __restrict__ Cout,
    const float* __restrict__ bias, const float* __restrict__ res,
    int K, int lda, int ldb, int ldc,
    long sA, long sB, long sC, float alpha) {
    __shared__ __align__(16) u16 Asm[8192];   // 2 x 8 KB
    __shared__ __align__(16) u16 Bsm[8192];

    unsigned flat = blockIdx.x + gridDim.x * (blockIdx.y + gridDim.y * blockIdx.z);
    unsigned nb = gridDim.x * gridDim.y * gridDim.z;
    unsigned lf = (flat & 7) * (nb >> 3) + (flat >> 3);
    unsigned pb = gridDim.x * gridDim.y;
    unsigned bz = lf / pb, rem = lf - bz * pb;
    unsigned by = rem / gridDim.x, bx = rem - by * gridDim.x;

    A += (size_t)bz * sA;
    B += (size_t)bz * sB;
    size_t zc = (size_t)bz * sC;

    int t = threadIdx.x;
    int wave = t >> 6, lane = t & 63;
    int wm = wave >> 1, wn = wave & 1;
    int rowA0 = by * 128;
    int colB0 = bx * 128;

    int c16log = (lane & 3) ^ ((lane >> 3) & 3);     // pre-swizzled global source
    const u16* aG[2]; const u16* bG[2]; u16* aL[2]; u16* bL[2];
#pragma unroll
    for (int j = 0; j < 2; j++) {
        int s = wave * 2 + j;
        int row = s * 16 + (lane >> 2);
        aL[j] = Asm + s * 512;
        bL[j] = Bsm + s * 512;
        aG[j] = A + (size_t)(rowA0 + row) * lda + c16log * 8;
        bG[j] = B + (size_t)(colB0 + row) * ldb + c16log * 8;
    }

    int kg = lane >> 4;
    int aoff[4], boff[4];
#pragma unroll
    for (int i = 0; i < 4; i++) {
        int ra = wm * 64 + i * 16 + (lane & 15);
        aoff[i] = ra * 32 + (kg ^ ((ra >> 1) & 3)) * 8;
        int rb = wn * 64 + i * 16 + (lane & 15);
        boff[i] = rb * 32 + (kg ^ ((rb >> 1) & 3)) * 8;
    }

#define STG_G(buf, ktE)                          \
    {                                            \
        gld16(aG[0] + (ktE), aL[0] + (buf) * 4096); \
        gld16(aG[1] + (ktE), aL[1] + (buf) * 4096); \
        gld16(bG[0] + (ktE), bL[0] + (buf) * 4096); \
        gld16(bG[1] + (ktE), bL[1] + (buf) * 4096); \
    }

    f32x4 acc[4][4] = {};
    int nk = K >> 5;
    STG_G(0, 0);
    __syncthreads();
    for (int kt = 0; kt < nk; kt++) {
        if (kt + 1 < nk) STG_G((kt + 1) & 1, (kt + 1) * 32);
        const u16* as = Asm + (kt & 1) * 4096;
        const u16* bs = Bsm + (kt & 1) * 4096;
        s16x8 af[4], bfr[4];
#pragma unroll
        for (int i = 0; i < 4; i++) {
            af[i]  = *(const s16x8*)(as + aoff[i]);
            bfr[i] = *(const s16x8*)(bs + boff[i]);
        }
#pragma unroll
        for (int mi = 0; mi < 4; mi++)
#pragma unroll
            for (int nj = 0; nj < 4; nj++)
                acc[mi][nj] = MFMA16(af[mi], bfr[nj], acc[mi][nj], 0, 0, 0);
        __syncthreads();
    }
#undef STG_G

    int r0 = rowA0 + wm * 64 + (lane >> 4) * 4;
    int c0c = colB0 + wn * 64 + (lane & 15);
#pragma unroll
    for (int mi = 0; mi < 4; mi++) {
#pragma unroll
        for (int nj = 0; nj < 4; nj++) {
            int c = c0c + nj * 16;
            float bv = BIAS ? bias[c] : 0.f;
            f32x4 v = acc[mi][nj];
#pragma unroll
            for (int j = 0; j < 4; j++) {
                int rr = r0 + mi * 16 + j;
                float val = v[j] * alpha + bv;
                if (RES) val += res[(size_t)rr * ldc + c];
                if (OUTF32) ((float*)Cout)[zc + (size_t)rr * ldc + c] = val;
                else        ((u16*)Cout)[zc + (size_t)rr * ldc + c] = f2bf(val);
            }
        }
    }
}

// ---------------------------------------------------------------- fused flash attention
// One block per (batch, 64-row q-tile); 512 thr = 8 waves as 2 row-teams x 4 col-teams.
// Phase 1: QK^T (K dbuf 2x64KB LDS, Q-frags streamed from L2, B-amp=2).
// Phase 2: full-row softmax (LDS cross-wave reduce).
// Phase 3: pack FULL P (64x1024 bf16 = 128KB LDS) -> acc1 dead before PV.
// Phase 4: PV with V^T frags read straight from global (L2-resident, XCD-local),
//          NO barriers in the PV loop. Epilogue: coalesced ao store via LDS repack.
__global__ __launch_bounds__(512, 2) void attn_fused(const u16* __restrict__ qkv,
                                                     const u16* __restrict__ vtg,
                                                     u16* __restrict__ ao) {
    __shared__ __align__(16) u16 S[65536];       // 128 KB

    unsigned flat = blockIdx.x;                  // 256 blocks
    unsigned lf = (flat & 7) * 32 + (flat >> 3); // 2 batches per XCD
    int b = lf >> 4, mt = lf & 15;

    int t = threadIdx.x, w = t >> 6, lane = t & 63;
    int rt = w >> 2, ct = w & 3;                 // row-team 0..1, col-team 0..3
    int l15 = lane & 15, kg = lane >> 4;

    const u16* kbase = qkv + (size_t)b * NTOK * 1536 + CH;
    int c16log = (lane & 3) ^ ((lane >> 3) & 3);

    // K staging: 64 segs of 16 rows; wave w stages segs w*8..w*8+7
    const u16* bG[8];
#pragma unroll
    for (int j = 0; j < 8; j++) {
        int row = (w * 8 + j) * 16 + (lane >> 2);
        bG[j] = kbase + (size_t)row * 1536 + c16log * 8;
    }
    // Q-frag row pointers (2 row-groups, frags read from global/L2 per kt)
    const u16* qp[2];
#pragma unroll
    for (int rg = 0; rg < 2; rg++)
        qp[rg] = qkv + (size_t)(b * NTOK + mt * 64 + rt * 32 + rg * 16 + l15) * 1536 + kg * 8;

    int rbb = ct * 256 + l15;                            // K B-frag base row
    int boffb = rbb * 32 + ((kg ^ ((rbb >> 1) & 3)) << 3);

    f32x4 acc1[2][16];
#pragma unroll
    for (int rg = 0; rg < 2; rg++)
#pragma unroll
        for (int nj = 0; nj < 16; nj++) acc1[rg][nj] = f32x4{0.f, 0.f, 0.f, 0.f};

#define KSTG(buf, kt)                                                        \
    { _Pragma("unroll")                                                      \
      for (int j = 0; j < 8; j++)                                            \
          gld16(bG[j] + (kt) * 32, S + (buf) * 32768 + (w * 8 + j) * 512); }

    KSTG(0, 0);
    s16x8 aqc[2], aqn[2];
    aqc[0] = *(const s16x8*)(qp[0]);
    aqc[1] = *(const s16x8*)(qp[1]);
    __syncthreads();
#pragma unroll
    for (int kt = 0; kt < 16; kt++) {
        if (kt < 15) {
            KSTG((kt + 1) & 1, kt + 1);
            aqn[0] = *(const s16x8*)(qp[0] + (kt + 1) * 32);
            aqn[1] = *(const s16x8*)(qp[1] + (kt + 1) * 32);
        }
        const u16* bb = S + (kt & 1) * 32768;
#pragma unroll
        for (int nj = 0; nj < 16; nj++) {
            s16x8 bf = *(const s16x8*)(bb + boffb + nj * 512);
            acc1[0][nj] = MFMA16(aqc[0], bf, acc1[0][nj], 0, 0, 0);
            acc1[1][nj] = MFMA16(aqc[1], bf, acc1[1][nj], 0, 0, 0);
        }
        if (kt < 15) { aqc[0] = aqn[0]; aqc[1] = aqn[1]; }
        __syncthreads();
    }
#undef KSTG

    // ---- softmax over full 1024 cols (scale folded into exp2) ----
    float* redm = (float*)S;          // [64][4]
    float* reds = redm + 256;         // [64][4]
    float mr[2][4], iv[2][4];
#pragma unroll
    for (int rg = 0; rg < 2; rg++)
#pragma unroll
        for (int j = 0; j < 4; j++) {
            float m = acc1[rg][0][j];
#pragma unroll
            for (int nj = 1; nj < 16; nj++) m = fmaxf(m, acc1[rg][nj][j]);
            for (int off = 1; off < 16; off <<= 1) m = fmaxf(m, __shfl_xor(m, off));
            mr[rg][j] = m;
        }
    if (l15 == 0) {
#pragma unroll
        for (int rg = 0; rg < 2; rg++)
#pragma unroll
            for (int j = 0; j < 4; j++)
                redm[(rt * 32 + rg * 16 + kg * 4 + j) * 4 + ct] = mr[rg][j];
    }
    __syncthreads();
#pragma unroll
    for (int rg = 0; rg < 2; rg++)
#pragma unroll
        for (int j = 0; j < 4; j++) {
            int row = rt * 32 + rg * 16 + kg * 4 + j;
            mr[rg][j] = fmaxf(fmaxf(redm[row * 4], redm[row * 4 + 1]),
                              fmaxf(redm[row * 4 + 2], redm[row * 4 + 3]));
        }
#pragma unroll
    for (int rg = 0; rg < 2; rg++)
#pragma unroll
        for (int j = 0; j < 4; j++) {
            float s = 0.f;
#pragma unroll
            for (int nj = 0; nj < 16; nj++) {
                float e = exp2f((acc1[rg][nj][j] - mr[rg][j]) * SEXP);
                acc1[rg][nj][j] = e;
                s += e;
            }
            for (int off = 1; off < 16; off <<= 1) s += __shfl_xor(s, off);
            if (l15 == 0) reds[(rt * 32 + rg * 16 + kg * 4 + j) * 4 + ct] = s;
        }
    __syncthreads();
#pragma unroll
    for (int rg = 0; rg < 2; rg++)
#pragma unroll
        for (int j = 0; j < 4; j++) {
            int row = rt * 32 + rg * 16 + kg * 4 + j;
            iv[rg][j] = 1.f / (reds[row * 4] + reds[row * 4 + 1] +
                               reds[row * 4 + 2] + reds[row * 4 + 3]);
        }
    __syncthreads();   // all reads of redm/reds done before pack overwrites S

    // ---- Phase 3: pack FULL P into S (64 rows x 1024 k, bf16, granule-XOR swizzle) ----
    // u16 idx = row*1024 + ((g ^ (row&7))<<3) + (k&7), g = k>>3. acc1 dead after this.
#pragma unroll
    for (int rg = 0; rg < 2; rg++)
#pragma unroll
        for (int nj = 0; nj < 16; nj++) {
            int k = ct * 256 + nj * 16 + l15;
            int g = k >> 3, ko = k & 7;
#pragma unroll
            for (int j = 0; j < 4; j++) {
                int row = rt * 32 + rg * 16 + kg * 4 + j;
                S[row * 1024 + ((g ^ (row & 7)) << 3) + ko] =
                    f2bf(acc1[rg][nj][j] * iv[rg][j]);
            }
        }
    __syncthreads();

    // ---- Phase 4: PV, no barriers. A=P from LDS, B=V^T frags from global (L2). ----
    f32x4 acc2[2][8];
#pragma unroll
    for (int rg = 0; rg < 2; rg++)
#pragma unroll
        for (int cj = 0; cj < 8; cj++) acc2[rg][cj] = f32x4{0.f, 0.f, 0.f, 0.f};

    const u16* vrow[8];
#pragma unroll
    for (int cj = 0; cj < 8; cj++)
        vrow[cj] = vtg + ((size_t)b * 512 + ct * 128 + cj * 16 + l15) * 1024 + kg * 8;

    int prowA[2] = {rt * 32 + l15, rt * 32 + 16 + l15};
    for (int c = 0; c < 32; c++) {                 // 32 k-chunks of 32
        s16x8 pa[2];
#pragma unroll
        for (int rg = 0; rg < 2; rg++) {
            int row = prowA[rg];
            pa[rg] = *(const s16x8*)(S + row * 1024 + (((c * 4 + kg) ^ (row & 7)) << 3));
        }
#pragma unroll
        for (int cj = 0; cj < 8; cj++) {
            s16x8 vf = *(const s16x8*)(vrow[cj] + c * 32);
            acc2[0][cj] = MFMA16(pa[0], vf, acc2[0][cj], 0, 0, 0);
            acc2[1][cj] = MFMA16(pa[1], vf, acc2[1][cj], 0, 0, 0);
        }
    }

    // ---- epilogue: repack acc2 through S (granule-swizzled) -> coalesced uint4 stores ----
    __syncthreads();   // P reads done before overwrite
#pragma unroll
    for (int rg = 0; rg < 2; rg++)
#pragma unroll
        for (int cj = 0; cj < 8; cj++)
#pragma unroll
            for (int j = 0; j < 4; j++) {
                int row = rt * 32 + rg * 16 + kg * 4 + j;
                int ch = ct * 128 + cj * 16 + l15;
                S[row * 512 + ((((ch >> 3) ^ (row & 7))) << 3) + (ch & 7)] =
                    f2bf(acc2[rg][cj][j]);
            }
    __syncthreads();
    u16* aop = ao + (size_t)(b * NTOK + mt * 64) * 512;
#pragma unroll
    for (int i = 0; i < 8; i++) {
        int f = i * 512 + t;              // granule index 0..4095
        int row = f >> 6, g = f & 63;
        uint4 v = *(const uint4*)(S + row * 512 + g * 8);
        *(uint4*)(aop + (size_t)row * 512 + ((g ^ (row & 7)) << 3)) = v;
    }
}

// ---------------------------------------------------------------- launch
extern "C" void kernel_launch(void* const* d_in, const int* in_sizes, int n_in,
                              void* d_out, int out_size, void* d_ws, size_t ws_size,
                              hipStream_t stream) {
    const float* x     = (const float*)d_in[0];
    const float* gamma = (const float*)d_in[1];
    const float* beta  = (const float*)d_in[2];
    const float* Wq    = (const float*)d_in[3];
    const float* bq    = (const float*)d_in[4];
    const float* Wk    = (const float*)d_in[5];
    const float* bk    = (const float*)d_in[6];
    const float* Wv    = (const float*)d_in[7];
    const float* bv    = (const float*)d_in[8];
    const float* Wp    = (const float*)d_in[9];
    const float* bp    = (const float*)d_in[10];
    float* out = (float*)d_out;

    const size_t SZ  = (size_t)MTOT * CH;          // 8,388,608
    const size_t NSZ = (size_t)NTOK * CH;          // per-batch activation

    char* p = (char*)d_ws;
    float*  xn    = (float*)p;   p += SZ * 4;                     // 33.5 MB
    u16*    xnb   = (u16*)p;     p += SZ * 2;                     // 16.8 MB
    u16*    qkvb  = (u16*)p;     p += (size_t)MTOT * 3 * CH * 2;  // 50.3 MB
    u16*    vt    = (u16*)p;     p += SZ * 2;                     // 16.8 MB
    u16*    ao    = (u16*)p;     p += SZ * 2;                     // 16.8 MB
    u16*    WTqkv = (u16*)p;     p += (size_t)3 * CH * CH * 2;    // 1.5 MB
    u16*    WTp   = (u16*)p;     p += (size_t)CH * CH * 2;        // 0.5 MB
    float*  bqkv  = (float*)p;   p += 3 * CH * 4;
    float2* stats = (float2*)p;

    dim3 blk(256);

    gn_stats<<<BATCH * NGRP, blk, 0, stream>>>(x, stats);
    gn_apply<<<2048, blk, 0, stream>>>(x, stats, gamma, beta, xn, xnb);
    weights_prep<<<dim3(8, 8, 4), blk, 0, stream>>>(Wq, Wk, Wv, Wp, WTqkv, WTp);
    prep_bias<<<6, blk, 0, stream>>>(bq, bk, bv, bqkv);

    // fused QKV: [16384x512] @ [512x1536] + bias -> qkvb bf16 (row stride 1536)
    gemm_bt<true, false, false><<<dim3(12, 128, 1), blk, 0, stream>>>(
        xnb, WTqkv, qkvb, bqkv, nullptr, CH, CH, CH, 3 * CH, 0, 0, 0, 1.f);

    // V slice -> V^T per batch
    vt_transpose<<<dim3(8, 16, BATCH), blk, 0, stream>>>(
        qkvb + 2 * CH, vt, NTOK, CH, 3 * CH, (long)NTOK * 3 * CH, (long)NSZ);

    // fused flash attention: scores+softmax+PV -> ao bf16
    attn_fused<<<256, 512, 0, stream>>>(qkvb, vt, ao);

    // proj + bias + residual(xn f32) -> out f32
    gemm_bt<true, true, true><<<dim3(4, 128, 1), blk, 0, stream>>>(
        ao, WTp, out, bp, xn, CH, CH, CH, CH, 0, 0, 0, 1.f);
}